// Round 10
// baseline (158.259 us; speedup 1.0000x reference)
//
#include <hip/hip_runtime.h>
#include <math.h>

#define H2 256
#define MAXDEG 128
#define APAD 520   // sA row stride (halves): 1040B rows -> 2-way banks (free)
#define HPAD 264   // hbuf row stride (halves): 528B rows -> 2-way banks (free)

typedef _Float16 f16x8 __attribute__((ext_vector_type(8)));
typedef _Float16 f16x4 __attribute__((ext_vector_type(4)));
typedef float f32x4 __attribute__((ext_vector_type(4)));

// ---------------------------------------------------------------------------
// Fused prep: zero cursor; nf fp32 -> cat fp16 cols [0,256) of [N][512];
// W1[512][256]->W1t[256][512] fp16; W2[256][256]->W2t[256][256] fp16.
__global__ __launch_bounds__(256) void prep(
        const float* __restrict__ nf, const float* __restrict__ W1,
        const float* __restrict__ W2, int* __restrict__ cursor,
        _Float16* __restrict__ cat, _Float16* __restrict__ W1t,
        _Float16* __restrict__ W2t, int n) {
    int flat = blockIdx.x * 256 + threadIdx.x;
    if (flat < n) cursor[flat] = 0;
    if (flat < 512 * 256) {                    // W1t idx = nn*512 + k
        int nn = flat >> 9, k = flat & 511;
        W1t[flat] = (_Float16)W1[(size_t)k * 256 + nn];
    } else if (flat < 512 * 256 + 256 * 256) { // W2t idx2 = nn*256 + k
        int idx2 = flat - 512 * 256;
        int nn = idx2 >> 8, k = idx2 & 255;
        W2t[idx2] = (_Float16)W2[(size_t)k * 256 + nn];
    }
    int wid  = threadIdx.x >> 6;
    int lane = threadIdx.x & 63;
    int row  = blockIdx.x * 4 + wid;
    if (row < n) {
        float4 v = ((const float4*)nf)[(size_t)row * 64 + lane];
        f16x4 h;
        h.x = (_Float16)v.x; h.y = (_Float16)v.y;
        h.z = (_Float16)v.z; h.w = (_Float16)v.w;
        *(f16x4*)&cat[(size_t)row * 512 + lane * 4] = h;
    }
}

// ---------------------------------------------------------------------------
__global__ void scatter_edges(const int* __restrict__ esrc, const int* __restrict__ edst,
                              int* __restrict__ cursor, int* __restrict__ bucket, int E) {
    int e = blockIdx.x * 256 + threadIdx.x;
    if (e >= E) return;
    int d = edst[e];
    int s = esrc[e];
    int r = atomicAdd(&cursor[d], 1);
    if (r < MAXDEG) bucket[d * MAXDEG + r] = s;
}

// ---------------------------------------------------------------------------
// pooled[i] = deg_i*nf[i] (fp32) - sum_{src} fp16(nf[src]).
// ONE NODE PER WAVE (grid N/4 -> 10000 waves, ~8/SIMD residency).
// MLP-16: 16 row-gathers in flight, 2 independent accumulators.
// Writes fp16 pooled into cat cols [256,512).
__global__ __launch_bounds__(256, 4) void agg_kernel(
        const float* __restrict__ nf, const int* __restrict__ cursor,
        const int* __restrict__ bucket, _Float16* __restrict__ cat, int n) {
    int wid  = threadIdx.x >> 6;
    int lane = threadIdx.x & 63;
    int node = blockIdx.x * 4 + wid;
    if (node >= n) return;
    int deg  = cursor[node];
    int degc = deg < MAXDEG ? deg : MAXDEG;
    const int* bk = bucket + (size_t)node * MAXDEG;
    float4 accA = make_float4(0.f, 0.f, 0.f, 0.f);
    float4 accB = make_float4(0.f, 0.f, 0.f, 0.f);
    int e = 0;
    for (; e + 16 <= degc; e += 16) {
        int4 sa = *(const int4*)&bk[e];
        int4 sb = *(const int4*)&bk[e + 4];
        int4 sc = *(const int4*)&bk[e + 8];
        int4 sd = *(const int4*)&bk[e + 12];
        f16x4 v0 = *(const f16x4*)&cat[(size_t)sa.x * 512 + lane * 4];
        f16x4 v1 = *(const f16x4*)&cat[(size_t)sa.y * 512 + lane * 4];
        f16x4 v2 = *(const f16x4*)&cat[(size_t)sa.z * 512 + lane * 4];
        f16x4 v3 = *(const f16x4*)&cat[(size_t)sa.w * 512 + lane * 4];
        f16x4 v4 = *(const f16x4*)&cat[(size_t)sb.x * 512 + lane * 4];
        f16x4 v5 = *(const f16x4*)&cat[(size_t)sb.y * 512 + lane * 4];
        f16x4 v6 = *(const f16x4*)&cat[(size_t)sb.z * 512 + lane * 4];
        f16x4 v7 = *(const f16x4*)&cat[(size_t)sb.w * 512 + lane * 4];
        f16x4 v8 = *(const f16x4*)&cat[(size_t)sc.x * 512 + lane * 4];
        f16x4 v9 = *(const f16x4*)&cat[(size_t)sc.y * 512 + lane * 4];
        f16x4 va = *(const f16x4*)&cat[(size_t)sc.z * 512 + lane * 4];
        f16x4 vb = *(const f16x4*)&cat[(size_t)sc.w * 512 + lane * 4];
        f16x4 vc = *(const f16x4*)&cat[(size_t)sd.x * 512 + lane * 4];
        f16x4 vd = *(const f16x4*)&cat[(size_t)sd.y * 512 + lane * 4];
        f16x4 ve = *(const f16x4*)&cat[(size_t)sd.z * 512 + lane * 4];
        f16x4 vf = *(const f16x4*)&cat[(size_t)sd.w * 512 + lane * 4];
        accA.x += (((float)v0.x + (float)v1.x) + ((float)v2.x + (float)v3.x))
                + (((float)v4.x + (float)v5.x) + ((float)v6.x + (float)v7.x));
        accA.y += (((float)v0.y + (float)v1.y) + ((float)v2.y + (float)v3.y))
                + (((float)v4.y + (float)v5.y) + ((float)v6.y + (float)v7.y));
        accA.z += (((float)v0.z + (float)v1.z) + ((float)v2.z + (float)v3.z))
                + (((float)v4.z + (float)v5.z) + ((float)v6.z + (float)v7.z));
        accA.w += (((float)v0.w + (float)v1.w) + ((float)v2.w + (float)v3.w))
                + (((float)v4.w + (float)v5.w) + ((float)v6.w + (float)v7.w));
        accB.x += (((float)v8.x + (float)v9.x) + ((float)va.x + (float)vb.x))
                + (((float)vc.x + (float)vd.x) + ((float)ve.x + (float)vf.x));
        accB.y += (((float)v8.y + (float)v9.y) + ((float)va.y + (float)vb.y))
                + (((float)vc.y + (float)vd.y) + ((float)ve.y + (float)vf.y));
        accB.z += (((float)v8.z + (float)v9.z) + ((float)va.z + (float)vb.z))
                + (((float)vc.z + (float)vd.z) + ((float)ve.z + (float)vf.z));
        accB.w += (((float)v8.w + (float)v9.w) + ((float)va.w + (float)vb.w))
                + (((float)vc.w + (float)vd.w) + ((float)ve.w + (float)vf.w));
    }
    for (; e + 8 <= degc; e += 8) {
        int4 sa = *(const int4*)&bk[e];
        int4 sb = *(const int4*)&bk[e + 4];
        f16x4 v0 = *(const f16x4*)&cat[(size_t)sa.x * 512 + lane * 4];
        f16x4 v1 = *(const f16x4*)&cat[(size_t)sa.y * 512 + lane * 4];
        f16x4 v2 = *(const f16x4*)&cat[(size_t)sa.z * 512 + lane * 4];
        f16x4 v3 = *(const f16x4*)&cat[(size_t)sa.w * 512 + lane * 4];
        f16x4 v4 = *(const f16x4*)&cat[(size_t)sb.x * 512 + lane * 4];
        f16x4 v5 = *(const f16x4*)&cat[(size_t)sb.y * 512 + lane * 4];
        f16x4 v6 = *(const f16x4*)&cat[(size_t)sb.z * 512 + lane * 4];
        f16x4 v7 = *(const f16x4*)&cat[(size_t)sb.w * 512 + lane * 4];
        accA.x += (((float)v0.x + (float)v1.x) + ((float)v2.x + (float)v3.x))
                + (((float)v4.x + (float)v5.x) + ((float)v6.x + (float)v7.x));
        accA.y += (((float)v0.y + (float)v1.y) + ((float)v2.y + (float)v3.y))
                + (((float)v4.y + (float)v5.y) + ((float)v6.y + (float)v7.y));
        accA.z += (((float)v0.z + (float)v1.z) + ((float)v2.z + (float)v3.z))
                + (((float)v4.z + (float)v5.z) + ((float)v6.z + (float)v7.z));
        accA.w += (((float)v0.w + (float)v1.w) + ((float)v2.w + (float)v3.w))
                + (((float)v4.w + (float)v5.w) + ((float)v6.w + (float)v7.w));
    }
    for (; e < degc; ++e) {
        int s = bk[e];
        f16x4 v = *(const f16x4*)&cat[(size_t)s * 512 + lane * 4];
        accA.x += (float)v.x; accA.y += (float)v.y;
        accA.z += (float)v.z; accA.w += (float)v.w;
    }
    float4 self = ((const float4*)nf)[(size_t)node * 64 + lane];
    float fd = (float)deg;
    f16x4 o;
    o.x = (_Float16)(fd * self.x - (accA.x + accB.x));
    o.y = (_Float16)(fd * self.y - (accA.y + accB.y));
    o.z = (_Float16)(fd * self.z - (accA.z + accB.z));
    o.w = (_Float16)(fd * self.w - (accA.w + accB.w));
    *(f16x4*)&cat[(size_t)node * 512 + 256 + lane * 4] = o;
}

// ---------------------------------------------------------------------------
// Fused fp16 MFMA GEMM: out = tanh((cat@W1t+b1)@W2t + b2).
// 256 thr / 4 waves; M-tile 16 (grid 625); wave n-tile 64 (j=4 frags).
// W fragments from L2 via depth-4 register pipeline (64 VGPR — allowed by
// launch_bounds(256,2) -> 256 cap); A via LDS w/ 1-step prefetch; h via LDS.
__global__ __launch_bounds__(256, 2) void gemm12(
        const _Float16* __restrict__ cat, const _Float16* __restrict__ W1t,
        const _Float16* __restrict__ W2t, const float* __restrict__ b1,
        const float* __restrict__ b2, float* __restrict__ out, int M) {
    __shared__ _Float16 sA[16 * APAD];     // 16.3 KB
    __shared__ _Float16 hbuf[16 * HPAD];   //  8.3 KB

    int tid = threadIdx.x, lane = tid & 63, wid = tid >> 6;   // wid 0..3
    int m0 = blockIdx.x * 16;
    int wn = wid * 64;
    int fm = lane & 15;
    int q  = lane >> 4;
    int fk = q * 8;

    // stage A: 16 rows x 512 halves = 1024 b128 groups; 4 passes of 256 thr
    for (int idx = tid; idx < 16 * 64; idx += 256) {
        int row = idx >> 6, g = (idx & 63) * 8;
        int r = m0 + row; if (r >= M) r = M - 1;   // clamp; junk rows unused
        *(uint4*)&sA[row * APAD + g] = *(const uint4*)&cat[(size_t)r * 512 + g];
    }
    __syncthreads();

    // ---- stage 1: h[16][256] = sA @ W1t + b1 ----
    size_t brow[4];
#pragma unroll
    for (int j = 0; j < 4; ++j) brow[j] = (size_t)(wn + j * 16 + fm) * 512 + fk;

    f16x8 wp[4][4];
#pragma unroll
    for (int s = 0; s < 4; ++s)
#pragma unroll
        for (int j = 0; j < 4; ++j)
            wp[s][j] = *(const f16x8*)&W1t[brow[j] + s * 32];

    f32x4 acc[4] = {};
    f16x8 a_cur = *(const f16x8*)&sA[fm * APAD + fk];
#pragma unroll
    for (int kb = 0; kb < 512; kb += 32) {
        int slot = (kb >> 5) & 3;
        f16x8 a_nxt;
        if (kb + 32 < 512) a_nxt = *(const f16x8*)&sA[fm * APAD + kb + 32 + fk];
        f16x8 w0 = wp[slot][0], w1 = wp[slot][1], w2 = wp[slot][2], w3 = wp[slot][3];
        if (kb + 128 < 512) {
#pragma unroll
            for (int j = 0; j < 4; ++j)
                wp[slot][j] = *(const f16x8*)&W1t[brow[j] + kb + 128];
        }
        acc[0] = __builtin_amdgcn_mfma_f32_16x16x32_f16(a_cur, w0, acc[0], 0, 0, 0);
        acc[1] = __builtin_amdgcn_mfma_f32_16x16x32_f16(a_cur, w1, acc[1], 0, 0, 0);
        acc[2] = __builtin_amdgcn_mfma_f32_16x16x32_f16(a_cur, w2, acc[2], 0, 0, 0);
        acc[3] = __builtin_amdgcn_mfma_f32_16x16x32_f16(a_cur, w3, acc[3], 0, 0, 0);
        if (kb + 32 < 512) a_cur = a_nxt;
    }

    // epilogue 1: hbuf[row][ncol], row = q*4+r, ncol = wn + j*16 + fm
#pragma unroll
    for (int j = 0; j < 4; ++j) {
        int ncol = wn + j * 16 + fm;
        float bv = b1[ncol];
#pragma unroll
        for (int r = 0; r < 4; ++r)
            hbuf[(q * 4 + r) * HPAD + ncol] = (_Float16)(acc[j][r] + bv);
    }
    __syncthreads();

    // ---- stage 2: out[16][256] = tanh(h @ W2t + b2) ----
    size_t brow2[4];
#pragma unroll
    for (int j = 0; j < 4; ++j) brow2[j] = (size_t)(wn + j * 16 + fm) * 256 + fk;

#pragma unroll
    for (int s = 0; s < 4; ++s)
#pragma unroll
        for (int j = 0; j < 4; ++j)
            wp[s][j] = *(const f16x8*)&W2t[brow2[j] + s * 32];

    f32x4 acc2[4] = {};
    a_cur = *(const f16x8*)&hbuf[fm * HPAD + fk];
#pragma unroll
    for (int kb = 0; kb < 256; kb += 32) {
        int slot = (kb >> 5) & 3;
        f16x8 a_nxt;
        if (kb + 32 < 256) a_nxt = *(const f16x8*)&hbuf[fm * HPAD + kb + 32 + fk];
        f16x8 w0 = wp[slot][0], w1 = wp[slot][1], w2 = wp[slot][2], w3 = wp[slot][3];
        if (kb + 128 < 256) {
#pragma unroll
            for (int j = 0; j < 4; ++j)
                wp[slot][j] = *(const f16x8*)&W2t[brow2[j] + kb + 128];
        }
        acc2[0] = __builtin_amdgcn_mfma_f32_16x16x32_f16(a_cur, w0, acc2[0], 0, 0, 0);
        acc2[1] = __builtin_amdgcn_mfma_f32_16x16x32_f16(a_cur, w1, acc2[1], 0, 0, 0);
        acc2[2] = __builtin_amdgcn_mfma_f32_16x16x32_f16(a_cur, w2, acc2[2], 0, 0, 0);
        acc2[3] = __builtin_amdgcn_mfma_f32_16x16x32_f16(a_cur, w3, acc2[3], 0, 0, 0);
        if (kb + 32 < 256) a_cur = a_nxt;
    }

    // epilogue 2
#pragma unroll
    for (int j = 0; j < 4; ++j) {
        int ncol = wn + j * 16 + fm;
        float bv = b2[ncol];
#pragma unroll
        for (int r = 0; r < 4; ++r) {
            int row = m0 + q * 4 + r;
            if (row < M) out[(size_t)row * 256 + ncol] = tanhf(acc2[j][r] + bv);
        }
    }
}

// ---------------------------------------------------------------------------
extern "C" void kernel_launch(void* const* d_in, const int* in_sizes, int n_in,
                              void* d_out, int out_size, void* d_ws, size_t ws_size,
                              hipStream_t stream) {
    const float* nf  = (const float*)d_in[0];   // [N, 256] fp32
    const float* W1  = (const float*)d_in[1];   // [512, 256]
    const float* b1  = (const float*)d_in[2];   // [256]
    const float* W2  = (const float*)d_in[3];   // [256, 256]
    const float* b2  = (const float*)d_in[4];   // [256]
    const int* esrc  = (const int*)d_in[5];     // [E]
    const int* edst  = (const int*)d_in[6];     // [E]
    float* out = (float*)d_out;                 // [N, 256] fp32

    int N = in_sizes[0] / H2;
    int E = in_sizes[5];

    char* ws = (char*)d_ws;
    size_t off = 0;
    auto take = [&](size_t bytes) { size_t o = off; off += (bytes + 255) / 256 * 256; return o; };
    int*       cursor = (int*)(ws + take((size_t)N * 4));
    int*       bucket = (int*)(ws + take((size_t)N * MAXDEG * 4));
    _Float16*  cat    = (_Float16*)(ws + take((size_t)N * 512 * 2));
    _Float16*  W1t    = (_Float16*)(ws + take(512 * 256 * 2));
    _Float16*  W2t    = (_Float16*)(ws + take(256 * 256 * 2));

    prep<<<(N + 3) / 4, 256, 0, stream>>>(nf, W1, W2, cursor, cat, W1t, W2t, N);
    scatter_edges<<<(E + 255) / 256, 256, 0, stream>>>(esrc, edst, cursor, bucket, E);
    agg_kernel<<<(N + 3) / 4, 256, 0, stream>>>(nf, cursor, bucket, cat, N);
    gemm12<<<(N + 15) / 16, 256, 0, stream>>>(cat, W1t, W2t, b1, b2, out, N);
}

// Round 11
// 156.849 us; speedup vs baseline: 1.0090x; 1.0090x over previous
//
#include <hip/hip_runtime.h>
#include <math.h>

#define H2 256
#define MAXDEG 128
#define APAD 520   // sA row stride (halves): 1040B rows -> 2-way banks (free)
#define HPAD 264   // hbuf row stride (halves): 528B rows -> 2-way banks (free)

typedef _Float16 f16x8 __attribute__((ext_vector_type(8)));
typedef _Float16 f16x4 __attribute__((ext_vector_type(4)));
typedef float f32x4 __attribute__((ext_vector_type(4)));

// ---------------------------------------------------------------------------
// Fused prep + scatter (cursor pre-zeroed by hipMemsetAsync):
//  - W1[512][256]->W1t[256][512] fp16; W2[256][256]->W2t[256][256] fp16
//  - nf fp32 -> cat fp16 [N][256]  (8 rows/block, 2 rows/wave)
//  - edge e: bucket[dst][atomic rank] = src
__global__ __launch_bounds__(256) void prep_scatter(
        const float* __restrict__ nf, const float* __restrict__ W1,
        const float* __restrict__ W2, const int* __restrict__ esrc,
        const int* __restrict__ edst, int* __restrict__ cursor,
        int* __restrict__ bucket, _Float16* __restrict__ cat,
        _Float16* __restrict__ W1t, _Float16* __restrict__ W2t,
        int n, int E) {
    int flat = blockIdx.x * 256 + threadIdx.x;
    if (flat < 512 * 256) {                    // W1t idx = nn*512 + k
        int nn = flat >> 9, k = flat & 511;
        W1t[flat] = (_Float16)W1[(size_t)k * 256 + nn];
    } else if (flat < 512 * 256 + 256 * 256) { // W2t idx2 = nn*256 + k
        int idx2 = flat - 512 * 256;
        int nn = idx2 >> 8, k = idx2 & 255;
        W2t[idx2] = (_Float16)W2[(size_t)k * 256 + nn];
    }
    int wid  = threadIdx.x >> 6;
    int lane = threadIdx.x & 63;
#pragma unroll
    for (int t = 0; t < 2; ++t) {
        int row = blockIdx.x * 8 + wid * 2 + t;
        if (row < n) {
            float4 v = ((const float4*)nf)[(size_t)row * 64 + lane];
            f16x4 h;
            h.x = (_Float16)v.x; h.y = (_Float16)v.y;
            h.z = (_Float16)v.z; h.w = (_Float16)v.w;
            *(f16x4*)&cat[(size_t)row * 256 + lane * 4] = h;
        }
    }
    if (flat < E) {
        int d = edst[flat];
        int s = esrc[flat];
        int r = atomicAdd(&cursor[d], 1);
        if (r < MAXDEG) bucket[d * MAXDEG + r] = s;
    }
}

// ---------------------------------------------------------------------------
// pooled[i] = deg_i*nf[i] (fp32) - sum_{src} fp16(nf[src]).
// One node per wave. PAIRED-ROW gather: one b128 instruction covers TWO rows
// (lanes 0-31 -> row e, lanes 32-63 -> row e+1, 16B/lane) -> half the load
// instructions per row vs 8B/lane. Halves combined via __shfl_down(.,32).
__global__ __launch_bounds__(256, 4) void agg_kernel(
        const float* __restrict__ nf, const int* __restrict__ cursor,
        const int* __restrict__ bucket, const _Float16* __restrict__ cat,
        _Float16* __restrict__ pooled, int n) {
    int wid  = threadIdx.x >> 6;
    int lane = threadIdx.x & 63;
    int node = blockIdx.x * 4 + wid;
    if (node >= n) return;
    int deg  = cursor[node];
    int degc = deg < MAXDEG ? deg : MAXDEG;
    const int* bk = bucket + (size_t)node * MAXDEG;

    int half = lane >> 5;          // 0: even row of pair, 1: odd row
    int c8   = (lane & 31) * 8;    // col base (halves), 16B per lane

    float acc[8] = {0.f, 0.f, 0.f, 0.f, 0.f, 0.f, 0.f, 0.f};
    int e = 0;
#pragma unroll 8
    for (; e + 2 <= degc; e += 2) {
        int s = bk[e + half];
        f16x8 v = *(const f16x8*)&cat[(size_t)s * 256 + c8];
#pragma unroll
        for (int k = 0; k < 8; ++k) acc[k] += (float)v[k];
    }
    if (e < degc) {                // odd tail row: lower half only
        int s = bk[e];
        f16x8 v = *(const f16x8*)&cat[(size_t)s * 256 + c8];
        if (half == 0) {
#pragma unroll
            for (int k = 0; k < 8; ++k) acc[k] += (float)v[k];
        }
    }
    // combine halves -> lanes 0-31 hold full column sums
    float tot[8];
#pragma unroll
    for (int k = 0; k < 8; ++k) tot[k] = acc[k] + __shfl_down(acc[k], 32);

    if (lane < 32) {
        // self row, cols [lane*8, lane*8+8) as two float4s
        float4 s0 = ((const float4*)nf)[(size_t)node * 64 + lane * 2];
        float4 s1 = ((const float4*)nf)[(size_t)node * 64 + lane * 2 + 1];
        float fd = (float)deg;
        f16x8 o;
        o[0] = (_Float16)(fd * s0.x - tot[0]);
        o[1] = (_Float16)(fd * s0.y - tot[1]);
        o[2] = (_Float16)(fd * s0.z - tot[2]);
        o[3] = (_Float16)(fd * s0.w - tot[3]);
        o[4] = (_Float16)(fd * s1.x - tot[4]);
        o[5] = (_Float16)(fd * s1.y - tot[5]);
        o[6] = (_Float16)(fd * s1.z - tot[6]);
        o[7] = (_Float16)(fd * s1.w - tot[7]);
        *(f16x8*)&pooled[(size_t)node * 256 + lane * 8] = o;
    }
}

// ---------------------------------------------------------------------------
// Fused fp16 MFMA GEMM: out = tanh(([cat|pooled]@W1t+b1)@W2t + b2).
// 256 thr / 4 waves; M-tile 16 (grid 625); wave n-tile 64 (j=4 frags).
// W fragments from L2 via depth-4 register pipeline; A via LDS w/ 1-step
// prefetch; h via LDS.
__global__ __launch_bounds__(256, 2) void gemm12(
        const _Float16* __restrict__ cat, const _Float16* __restrict__ pooled,
        const _Float16* __restrict__ W1t, const _Float16* __restrict__ W2t,
        const float* __restrict__ b1, const float* __restrict__ b2,
        float* __restrict__ out, int M) {
    __shared__ _Float16 sA[16 * APAD];     // 16.3 KB
    __shared__ _Float16 hbuf[16 * HPAD];   //  8.3 KB

    int tid = threadIdx.x, lane = tid & 63, wid = tid >> 6;   // wid 0..3
    int m0 = blockIdx.x * 16;
    int wn = wid * 64;
    int fm = lane & 15;
    int q  = lane >> 4;
    int fk = q * 8;

    // stage A: 16 rows x 512 halves (cat cols [0,256) | pooled cols [256,512))
    for (int idx = tid; idx < 16 * 64; idx += 256) {
        int row = idx >> 6, g = (idx & 63) * 8;
        int r = m0 + row; if (r >= M) r = M - 1;   // clamp; junk rows unused
        uint4 val = (g < 256) ? *(const uint4*)&cat[(size_t)r * 256 + g]
                              : *(const uint4*)&pooled[(size_t)r * 256 + (g - 256)];
        *(uint4*)&sA[row * APAD + g] = val;
    }
    __syncthreads();

    // ---- stage 1: h[16][256] = sA @ W1t + b1 ----
    size_t brow[4];
#pragma unroll
    for (int j = 0; j < 4; ++j) brow[j] = (size_t)(wn + j * 16 + fm) * 512 + fk;

    f16x8 wp[4][4];
#pragma unroll
    for (int s = 0; s < 4; ++s)
#pragma unroll
        for (int j = 0; j < 4; ++j)
            wp[s][j] = *(const f16x8*)&W1t[brow[j] + s * 32];

    f32x4 acc[4] = {};
    f16x8 a_cur = *(const f16x8*)&sA[fm * APAD + fk];
#pragma unroll
    for (int kb = 0; kb < 512; kb += 32) {
        int slot = (kb >> 5) & 3;
        f16x8 a_nxt;
        if (kb + 32 < 512) a_nxt = *(const f16x8*)&sA[fm * APAD + kb + 32 + fk];
        f16x8 w0 = wp[slot][0], w1 = wp[slot][1], w2 = wp[slot][2], w3 = wp[slot][3];
        if (kb + 128 < 512) {
#pragma unroll
            for (int j = 0; j < 4; ++j)
                wp[slot][j] = *(const f16x8*)&W1t[brow[j] + kb + 128];
        }
        acc[0] = __builtin_amdgcn_mfma_f32_16x16x32_f16(a_cur, w0, acc[0], 0, 0, 0);
        acc[1] = __builtin_amdgcn_mfma_f32_16x16x32_f16(a_cur, w1, acc[1], 0, 0, 0);
        acc[2] = __builtin_amdgcn_mfma_f32_16x16x32_f16(a_cur, w2, acc[2], 0, 0, 0);
        acc[3] = __builtin_amdgcn_mfma_f32_16x16x32_f16(a_cur, w3, acc[3], 0, 0, 0);
        if (kb + 32 < 512) a_cur = a_nxt;
    }

    // epilogue 1: hbuf[row][ncol], row = q*4+r, ncol = wn + j*16 + fm
#pragma unroll
    for (int j = 0; j < 4; ++j) {
        int ncol = wn + j * 16 + fm;
        float bv = b1[ncol];
#pragma unroll
        for (int r = 0; r < 4; ++r)
            hbuf[(q * 4 + r) * HPAD + ncol] = (_Float16)(acc[j][r] + bv);
    }
    __syncthreads();

    // ---- stage 2: out[16][256] = tanh(h @ W2t + b2) ----
    size_t brow2[4];
#pragma unroll
    for (int j = 0; j < 4; ++j) brow2[j] = (size_t)(wn + j * 16 + fm) * 256 + fk;

#pragma unroll
    for (int s = 0; s < 4; ++s)
#pragma unroll
        for (int j = 0; j < 4; ++j)
            wp[s][j] = *(const f16x8*)&W2t[brow2[j] + s * 32];

    f32x4 acc2[4] = {};
    a_cur = *(const f16x8*)&hbuf[fm * HPAD + fk];
#pragma unroll
    for (int kb = 0; kb < 256; kb += 32) {
        int slot = (kb >> 5) & 3;
        f16x8 a_nxt;
        if (kb + 32 < 256) a_nxt = *(const f16x8*)&hbuf[fm * HPAD + kb + 32 + fk];
        f16x8 w0 = wp[slot][0], w1 = wp[slot][1], w2 = wp[slot][2], w3 = wp[slot][3];
        if (kb + 128 < 256) {
#pragma unroll
            for (int j = 0; j < 4; ++j)
                wp[slot][j] = *(const f16x8*)&W2t[brow2[j] + kb + 128];
        }
        acc2[0] = __builtin_amdgcn_mfma_f32_16x16x32_f16(a_cur, w0, acc2[0], 0, 0, 0);
        acc2[1] = __builtin_amdgcn_mfma_f32_16x16x32_f16(a_cur, w1, acc2[1], 0, 0, 0);
        acc2[2] = __builtin_amdgcn_mfma_f32_16x16x32_f16(a_cur, w2, acc2[2], 0, 0, 0);
        acc2[3] = __builtin_amdgcn_mfma_f32_16x16x32_f16(a_cur, w3, acc2[3], 0, 0, 0);
        if (kb + 32 < 256) a_cur = a_nxt;
    }

    // epilogue 2
#pragma unroll
    for (int j = 0; j < 4; ++j) {
        int ncol = wn + j * 16 + fm;
        float bv = b2[ncol];
#pragma unroll
        for (int r = 0; r < 4; ++r) {
            int row = m0 + q * 4 + r;
            if (row < M) out[(size_t)row * 256 + ncol] = tanhf(acc2[j][r] + bv);
        }
    }
}

// ---------------------------------------------------------------------------
extern "C" void kernel_launch(void* const* d_in, const int* in_sizes, int n_in,
                              void* d_out, int out_size, void* d_ws, size_t ws_size,
                              hipStream_t stream) {
    const float* nf  = (const float*)d_in[0];   // [N, 256] fp32
    const float* W1  = (const float*)d_in[1];   // [512, 256]
    const float* b1  = (const float*)d_in[2];   // [256]
    const float* W2  = (const float*)d_in[3];   // [256, 256]
    const float* b2  = (const float*)d_in[4];   // [256]
    const int* esrc  = (const int*)d_in[5];     // [E]
    const int* edst  = (const int*)d_in[6];     // [E]
    float* out = (float*)d_out;                 // [N, 256] fp32

    int N = in_sizes[0] / H2;
    int E = in_sizes[5];

    char* ws = (char*)d_ws;
    size_t off = 0;
    auto take = [&](size_t bytes) { size_t o = off; off += (bytes + 255) / 256 * 256; return o; };
    int*       cursor = (int*)(ws + take((size_t)N * 4));
    int*       bucket = (int*)(ws + take((size_t)N * MAXDEG * 4));
    _Float16*  cat    = (_Float16*)(ws + take((size_t)N * 256 * 2));
    _Float16*  pooled = (_Float16*)(ws + take((size_t)N * 256 * 2));
    _Float16*  W1t    = (_Float16*)(ws + take(512 * 256 * 2));
    _Float16*  W2t    = (_Float16*)(ws + take(256 * 256 * 2));

    hipMemsetAsync(cursor, 0, (size_t)N * 4, stream);

    int gW  = (512 * 256 + 256 * 256 + 255) / 256;   // W transpose coverage
    int gE  = (E + 255) / 256;                        // edge coverage
    int gR  = (N + 7) / 8;                            // cat-row coverage
    int g1  = gE > gW ? gE : gW; if (gR > g1) g1 = gR;
    prep_scatter<<<g1, 256, 0, stream>>>(nf, W1, W2, esrc, edst, cursor,
                                         bucket, cat, W1t, W2t, N, E);
    agg_kernel<<<(N + 3) / 4, 256, 0, stream>>>(nf, cursor, bucket, cat, pooled, N);
    gemm12<<<(N + 15) / 16, 256, 0, stream>>>(cat, pooled, W1t, W2t, b1, b2, out, N);
}